// Round 2
// baseline (795.734 us; speedup 1.0000x reference)
//
#include <hip/hip_runtime.h>
#include <cstdint>
#include <cstddef>

// ---------------------------------------------------------------------------
// Problem constants (from reference):
//   B=4, T=8160, D=1024, N=8 heads, H=128, W=12, L=12, R=0, C=24, CAP=50
//   M = B*T = 32640 rows.  q/k/v = x @ wq/wk/wv.  logit(qt,kt) =
//   s*(q.(k+emb[qt-kt])), d in [0,12], softcap 50*tanh(./50), softmax, PV.
// All float tensors are fp32 in global memory (per reference dtypes).
// Internally: x and weights are converted to bf16 for the MFMA GEMM.
// ---------------------------------------------------------------------------

typedef __bf16 bf16_t;
typedef float  floatx4 __attribute__((ext_vector_type(4)));
typedef __bf16 bf16x8  __attribute__((ext_vector_type(8)));

#define GLDS16(gp, lp)                                                        \
  __builtin_amdgcn_global_load_lds(                                           \
      (const __attribute__((address_space(1))) void*)(gp),                    \
      (__attribute__((address_space(3))) void*)(lp), 16, 0, 0)

static constexpr int kT     = 8160;
static constexpr int kM     = 4 * kT;    // 32640
static constexpr int kHeads = 8;
static constexpr int kW     = 12;
static constexpr int kU     = kT / kW;   // 680

// ---------------------------------------------------------------------------
// Kernel 0: convert x (fp32) -> bf16, 8 elements/thread.
// ---------------------------------------------------------------------------
__global__ __launch_bounds__(256) void convert_x(const float* __restrict__ X,
                                                 bf16_t* __restrict__ Xb) {
  const size_t i = ((size_t)blockIdx.x * 256 + threadIdx.x) * 8;
  float4 a = *(const float4*)(X + i);
  float4 b = *(const float4*)(X + i + 4);
  bf16x8 o;
  o[0] = (bf16_t)a.x; o[1] = (bf16_t)a.y; o[2] = (bf16_t)a.z; o[3] = (bf16_t)a.w;
  o[4] = (bf16_t)b.x; o[5] = (bf16_t)b.y; o[6] = (bf16_t)b.z; o[7] = (bf16_t)b.w;
  *(bf16x8*)(Xb + i) = o;
}

// ---------------------------------------------------------------------------
// Kernel 1: sinusoidal position embedding projected through pos_proj (fp32).
//   pe[d][f] = sum_dd ts(d)[dd] * pp[dd][f],  d in [0,12], f in [0,1024)
// ---------------------------------------------------------------------------
__global__ __launch_bounds__(256) void posemb_k(const float* __restrict__ pp,
                                                float* __restrict__ pe) {
  __shared__ float st[1024];
  const int d   = blockIdx.x;      // relative distance 0..12
  const int tid = threadIdx.x;
  const float dpos = (float)d;
  for (int i = tid; i < 1024; i += 256) {
    int idx = i & 511;
    float freq = expf(-(float)idx * (9.2103403719761836f / 511.0f));
    float a = dpos * freq;
    st[i] = (i < 512) ? sinf(a) : cosf(a);
  }
  __syncthreads();
  float a0 = 0.f, a1 = 0.f, a2 = 0.f, a3 = 0.f;
  const int f = tid;
  for (int dd = 0; dd < 1024; ++dd) {
    float ts = st[dd];
    const float* row = pp + (size_t)dd * 1024 + f;
    a0 += ts * row[0];
    a1 += ts * row[256];
    a2 += ts * row[512];
    a3 += ts * row[768];
  }
  float* o = pe + (size_t)d * 1024 + f;
  o[0] = a0; o[256] = a1; o[512] = a2; o[768] = a3;
}

// ---------------------------------------------------------------------------
// Kernel 2: transpose the three fp32 weight matrices into bf16 Wt[3072][1024];
// row n of Wt = column n of W, so GEMM B-tiles are k-contiguous.
// ---------------------------------------------------------------------------
__global__ __launch_bounds__(256) void transpose_w(const float* __restrict__ Wq,
                                                   const float* __restrict__ Wk,
                                                   const float* __restrict__ Wv,
                                                   bf16_t* __restrict__ Wt) {
  __shared__ float tile[64][65];
  const int g = blockIdx.z;
  const float* W = (g == 0) ? Wq : (g == 1) ? Wk : Wv;
  bf16_t* O = Wt + (size_t)g * 1024 * 1024;
  const int k0 = blockIdx.x * 64, n0 = blockIdx.y * 64;
  const int col = threadIdx.x & 63, r4 = threadIdx.x >> 6;
#pragma unroll
  for (int i = 0; i < 16; ++i) {
    int row = i * 4 + r4;
    tile[row][col] = W[(size_t)(k0 + row) * 1024 + n0 + col];
  }
  __syncthreads();
#pragma unroll
  for (int i = 0; i < 16; ++i) {
    int row = i * 4 + r4;   // n offset
    O[(size_t)(n0 + row) * 1024 + k0 + col] = (bf16_t)tile[col][row];
  }
}

// ---------------------------------------------------------------------------
// Kernel 3: fused QKV GEMM (bf16 MFMA).  C[m][n] = sum_k Xb[m][k] * Wt[n][k]
//   M=32640, N=3072, K=1024.  128x128x32 tiles, 4 waves each 64x64,
//   mfma_f32_16x16x32_bf16, global_load_lds width-16 staging (m97 structure).
// ---------------------------------------------------------------------------
__global__ __launch_bounds__(256) void qkv_gemm(const bf16_t* __restrict__ X,
                                                const bf16_t* __restrict__ Wt,
                                                bf16_t* __restrict__ QKV) {
  __shared__ bf16_t As[128 * 32];
  __shared__ bf16_t Bs[128 * 32];
  const int m0   = blockIdx.x * 128;
  const int n0   = blockIdx.y * 128;
  const int tid  = threadIdx.x;
  const int wave = tid >> 6;
  const int lane = tid & 63;
  const int wm   = (wave >> 1) * 64;
  const int wn   = (wave & 1) * 64;
  const int qd   = lane >> 4;      // quad 0..3
  const int lr   = lane & 15;

  floatx4 acc[4][4] = {};

  // staging: 512 16B-chunks per tile; chunk c -> row c>>2, elem off (c&3)*8
  const int c0 = (wave * 2 + 0) * 64 + lane;
  const int c1 = (wave * 2 + 1) * 64 + lane;
  const int r0 = c0 >> 2, o0 = (c0 & 3) * 8;
  const int r1 = c1 >> 2, o1 = (c1 & 3) * 8;
  const bf16_t* xg0 = X + (size_t)(m0 + r0) * 1024 + o0;
  const bf16_t* xg1 = X + (size_t)(m0 + r1) * 1024 + o1;
  const bf16_t* wg0 = Wt + (size_t)(n0 + r0) * 1024 + o0;
  const bf16_t* wg1 = Wt + (size_t)(n0 + r1) * 1024 + o1;
  bf16_t* lA0 = As + (wave * 2 + 0) * 512;   // wave-uniform LDS base
  bf16_t* lA1 = As + (wave * 2 + 1) * 512;
  bf16_t* lB0 = Bs + (wave * 2 + 0) * 512;
  bf16_t* lB1 = Bs + (wave * 2 + 1) * 512;

  for (int kk = 0; kk < 1024; kk += 32) {
    GLDS16(xg0 + kk, lA0);
    GLDS16(xg1 + kk, lA1);
    GLDS16(wg0 + kk, lB0);
    GLDS16(wg1 + kk, lB1);
    __syncthreads();

    bf16x8 a[4], b[4];
#pragma unroll
    for (int im = 0; im < 4; ++im)
      a[im] = *(const bf16x8*)(As + (wm + im * 16 + lr) * 32 + qd * 8);
#pragma unroll
    for (int in = 0; in < 4; ++in)
      b[in] = *(const bf16x8*)(Bs + (wn + in * 16 + lr) * 32 + qd * 8);
#pragma unroll
    for (int im = 0; im < 4; ++im)
#pragma unroll
      for (int in = 0; in < 4; ++in)
        acc[im][in] = __builtin_amdgcn_mfma_f32_16x16x32_bf16(
            a[im], b[in], acc[im][in], 0, 0, 0);
    __syncthreads();
  }

  // epilogue: C/D layout col=lane&15, row=quad*4+reg  (verified m89)
#pragma unroll
  for (int im = 0; im < 4; ++im)
#pragma unroll
    for (int in = 0; in < 4; ++in)
#pragma unroll
      for (int r = 0; r < 4; ++r) {
        int m = m0 + wm + im * 16 + qd * 4 + r;
        int n = n0 + wn + in * 16 + lr;
        QKV[(size_t)m * 3072 + n] = (bf16_t)acc[im][in][r];
      }
}

// ---------------------------------------------------------------------------
// Kernel 4: local attention.  One block per (u, head, batch).
//   logits over d in [0,12]: kt = u*12 + w - d (valid iff kt >= 0)
// ---------------------------------------------------------------------------
__global__ __launch_bounds__(256) void attn_k(const bf16_t* __restrict__ QKV,
                                              const float* __restrict__ PE,
                                              float* __restrict__ OUT) {
  __shared__ float qs[12 * 129];
  __shared__ float ks[24 * 129];
  __shared__ float vs[24 * 129];
  __shared__ float pes[13 * 129];
  __shared__ float p[12 * 13];

  const int u   = blockIdx.x;
  const int n   = blockIdx.y;
  const int b   = blockIdx.z;
  const int tid = threadIdx.x;
  const int t0  = u * 12 - 12;                 // time of context row c=0
  const size_t bbase = (size_t)b * kT;

  // ---- stage q (12 rows x 128, 16B vector loads) ----
  for (int i = tid; i < 12 * 16; i += 256) {
    int row = i >> 4, ch = i & 15;
    bf16x8 v8 = *(const bf16x8*)(QKV + (bbase + u * 12 + row) * 3072 + n * 128 + ch * 8);
    int o = row * 129 + ch * 8;
#pragma unroll
    for (int j = 0; j < 8; ++j) qs[o + j] = (float)v8[j];
  }
  // ---- stage k, v (24 rows x 128) ----
  for (int i = tid; i < 24 * 16; i += 256) {
    int row = i >> 4, ch = i & 15;
    int t = t0 + row;
    int o = row * 129 + ch * 8;
    if (t < 0) {
#pragma unroll
      for (int j = 0; j < 8; ++j) { ks[o + j] = 0.f; vs[o + j] = 0.f; }
    } else {
      size_t base = (bbase + t) * 3072 + n * 128 + ch * 8;
      bf16x8 k8 = *(const bf16x8*)(QKV + base + 1024);
      bf16x8 v8 = *(const bf16x8*)(QKV + base + 2048);
#pragma unroll
      for (int j = 0; j < 8; ++j) { ks[o + j] = (float)k8[j]; vs[o + j] = (float)v8[j]; }
    }
  }
  // ---- stage pe (13 rows x 128, fp32) ----
  for (int i = tid; i < 13 * 32; i += 256) {
    int dd = i >> 5, ch = i & 31;
    float4 pv = *(const float4*)(PE + (size_t)dd * 1024 + n * 128 + ch * 4);
    int o = dd * 129 + ch * 4;
    pes[o] = pv.x; pes[o + 1] = pv.y; pes[o + 2] = pv.z; pes[o + 3] = pv.w;
  }
  __syncthreads();

  // ---- logits: 12 queries x 13 distances ----
  if (tid < 156) {
    int w = tid / 13, d = tid - w * 13;
    int t = u * 12 + w - d;
    float lg = -1e30f;
    if (t >= 0) {
      int cc = w - d + 12;                 // context row of that key
      const float* qp = qs + w * 129;
      const float* kp = ks + cc * 129;
      const float* ep = pes + d * 129;
      float acc = 0.f;
#pragma unroll 8
      for (int h = 0; h < 128; ++h) acc += qp[h] * (kp[h] + ep[h]);
      acc *= 0.08838834764831845f;         // H^-0.5
      lg = 50.0f * tanhf(acc * 0.02f);     // soft cap
    }
    p[tid] = lg;                           // tid == w*13 + d
  }
  __syncthreads();

  // ---- softmax per query row ----
  if (tid < 12) {
    float mx = -1e30f;
#pragma unroll
    for (int d = 0; d < 13; ++d) mx = fmaxf(mx, p[tid * 13 + d]);
    float e[13], sum = 0.f;
#pragma unroll
    for (int d = 0; d < 13; ++d) { e[d] = expf(p[tid * 13 + d] - mx); sum += e[d]; }
    float inv = 1.0f / sum;
#pragma unroll
    for (int d = 0; d < 13; ++d) p[tid * 13 + d] = e[d] * inv;
  }
  __syncthreads();

  // ---- PV: out[w][h] = sum_d p[w][d] * v[w-d+12][h] ----
  for (int i = tid; i < 12 * 128; i += 256) {
    int w = i >> 7, h = i & 127;
    const float* pw = p + w * 13;
    float acc = 0.f;
#pragma unroll
    for (int d = 0; d < 13; ++d) acc += pw[d] * vs[(w - d + 12) * 129 + h];
    OUT[(bbase + u * 12 + w) * 1024 + n * 128 + h] = acc;
  }
}

// ---------------------------------------------------------------------------
// Launch
// ---------------------------------------------------------------------------
extern "C" void kernel_launch(void* const* d_in, const int* in_sizes, int n_in,
                              void* d_out, int out_size, void* d_ws, size_t ws_size,
                              hipStream_t stream) {
  const float* x  = (const float*)d_in[0];
  // d_in[1] = mask (all True) and d_in[2] = causal_valid_mask are analytic; unused.
  const float* wq = (const float*)d_in[3];
  const float* wk = (const float*)d_in[4];
  const float* wv = (const float*)d_in[5];
  const float* pp = (const float*)d_in[6];

  char* ws = (char*)d_ws;
  float*  pe  = (float*)ws;                                    // 13*1024*4 = 53 KB
  bf16_t* Wt  = (bf16_t*)(ws + (1u << 16));                    // 6 MB
  bf16_t* Xb  = (bf16_t*)(ws + (1u << 16) + 6u * 1024 * 1024); // 33.4M * 2 = 64 MB
  bf16_t* QKV = (bf16_t*)(ws + (1u << 16) + 6u * 1024 * 1024 +
                          (size_t)kM * 1024 * 2);              // 191 MB
  float* out = (float*)d_out;

  convert_x<<<kM * 1024 / (256 * 8), 256, 0, stream>>>(x, Xb);
  posemb_k<<<13, 256, 0, stream>>>(pp, pe);
  transpose_w<<<dim3(16, 16, 3), 256, 0, stream>>>(wq, wk, wv, Wt);
  qkv_gemm<<<dim3(kM / 128, 3072 / 128), 256, 0, stream>>>(Xb, Wt, QKV);
  attn_k<<<dim3(kU, kHeads, 4), 256, 0, stream>>>(QKV, pe, out);
}

// Round 3
// 730.730 us; speedup vs baseline: 1.0890x; 1.0890x over previous
//
#include <hip/hip_runtime.h>
#include <cstdint>
#include <cstddef>

// ---------------------------------------------------------------------------
// B=4, T=8160, D=1024, N=8 heads, H=128, W=12, L=12, R=0, C=24, CAP=50
// logit(qt,kt) = s*(q.(k + emb[qt-kt])), d = qt-kt in [0,12], softcap, softmax.
// Position term folded into the QKV GEMM:  q.pe_d = x . (Wq @ pe_d), appended
// as 128 extra B-rows (104 real (n,d) pairs + 24 zero pad) -> GEMM N = 3200.
// QKV row: [0,1024)=q [1024,2048)=k [2048,3072)=v [3072+n*13+d]=qpe.
// ---------------------------------------------------------------------------

typedef __bf16 bf16_t;
typedef float  floatx4 __attribute__((ext_vector_type(4)));
typedef __bf16 bf16x8  __attribute__((ext_vector_type(8)));
typedef __bf16 bf16x4  __attribute__((ext_vector_type(4)));

#define GLDS16(gp, lp)                                                        \
  __builtin_amdgcn_global_load_lds(                                           \
      (const __attribute__((address_space(1))) void*)(gp),                    \
      (__attribute__((address_space(3))) void*)(lp), 16, 0, 0)

static constexpr int kT     = 8160;
static constexpr int kM     = 4 * kT;    // 32640
static constexpr int kU     = kT / 12;   // 680
static constexpr int kNC    = 3200;      // GEMM N (3072 qkv + 128 qpe block)

// ---------------------------------------------------------------------------
// Kernel 0: convert x (fp32) -> bf16, 8 elements/thread.
// ---------------------------------------------------------------------------
__global__ __launch_bounds__(256) void convert_x(const float* __restrict__ X,
                                                 bf16_t* __restrict__ Xb) {
  const size_t i = ((size_t)blockIdx.x * 256 + threadIdx.x) * 8;
  float4 a = *(const float4*)(X + i);
  float4 b = *(const float4*)(X + i + 4);
  bf16x8 o;
  o[0] = (bf16_t)a.x; o[1] = (bf16_t)a.y; o[2] = (bf16_t)a.z; o[3] = (bf16_t)a.w;
  o[4] = (bf16_t)b.x; o[5] = (bf16_t)b.y; o[6] = (bf16_t)b.z; o[7] = (bf16_t)b.w;
  *(bf16x8*)(Xb + i) = o;
}

// ---------------------------------------------------------------------------
// Kernel 1: pe[d][f] = sum_dd ts(d)[dd] * pos_proj[dd][f]   (fp32)
// ---------------------------------------------------------------------------
__global__ __launch_bounds__(256) void posemb_k(const float* __restrict__ pp,
                                                float* __restrict__ pe) {
  __shared__ float st[1024];
  const int d   = blockIdx.x;      // relative distance 0..12
  const int tid = threadIdx.x;
  const float dpos = (float)d;
  for (int i = tid; i < 1024; i += 256) {
    int idx = i & 511;
    float freq = expf(-(float)idx * (9.2103403719761836f / 511.0f));
    float a = dpos * freq;
    st[i] = (i < 512) ? sinf(a) : cosf(a);
  }
  __syncthreads();
  float a0 = 0.f, a1 = 0.f, a2 = 0.f, a3 = 0.f;
  const int f = tid;
  for (int dd = 0; dd < 1024; ++dd) {
    float ts = st[dd];
    const float* row = pp + (size_t)dd * 1024 + f;
    a0 += ts * row[0];
    a1 += ts * row[256];
    a2 += ts * row[512];
    a3 += ts * row[768];
  }
  float* o = pe + (size_t)d * 1024 + f;
  o[0] = a0; o[256] = a1; o[512] = a2; o[768] = a3;
}

// ---------------------------------------------------------------------------
// Kernel 2: transpose fp32 weights -> bf16 Wt[3072][1024] (row n = col n of W)
// ---------------------------------------------------------------------------
__global__ __launch_bounds__(256) void transpose_w(const float* __restrict__ Wq,
                                                   const float* __restrict__ Wk,
                                                   const float* __restrict__ Wv,
                                                   bf16_t* __restrict__ Wt) {
  __shared__ float tile[64][65];
  const int g = blockIdx.z;
  const float* W = (g == 0) ? Wq : (g == 1) ? Wk : Wv;
  bf16_t* O = Wt + (size_t)g * 1024 * 1024;
  const int k0 = blockIdx.x * 64, n0 = blockIdx.y * 64;
  const int col = threadIdx.x & 63, r4 = threadIdx.x >> 6;
#pragma unroll
  for (int i = 0; i < 16; ++i) {
    int row = i * 4 + r4;
    tile[row][col] = W[(size_t)(k0 + row) * 1024 + n0 + col];
  }
  __syncthreads();
#pragma unroll
  for (int i = 0; i < 16; ++i) {
    int row = i * 4 + r4;   // n offset
    O[(size_t)(n0 + row) * 1024 + k0 + col] = (bf16_t)tile[col][row];
  }
}

// ---------------------------------------------------------------------------
// Kernel 2b: W2 rows.  Wt[3072+idx][k] = sum_h pe[d][n*128+h]*Wt[n*128+h][k]
// idx = n*13+d for idx<104, zero pad for idx in [104,128).
// ---------------------------------------------------------------------------
__global__ __launch_bounds__(256) void pe2w(const float* __restrict__ pe,
                                            bf16_t* __restrict__ Wt) {
  const int idx = blockIdx.x;              // 0..127
  const int tid = threadIdx.x;
  bf16_t* out = Wt + (size_t)(3072 + idx) * 1024;
  if (idx >= 104) {
    bf16x4 z = {};
    *(bf16x4*)(out + tid * 4) = z;
    return;
  }
  const int n = idx / 13, d = idx - n * 13;
  __shared__ float peh[128];
  if (tid < 128) peh[tid] = pe[(size_t)d * 1024 + n * 128 + tid];
  __syncthreads();
  float acc[4] = {};
  const bf16_t* wb = Wt + (size_t)(n * 128) * 1024 + tid * 4;
  for (int h = 0; h < 128; ++h) {
    bf16x4 w4 = *(const bf16x4*)(wb + (size_t)h * 1024);
    float s = peh[h];
    acc[0] += s * (float)w4[0];
    acc[1] += s * (float)w4[1];
    acc[2] += s * (float)w4[2];
    acc[3] += s * (float)w4[3];
  }
  bf16x4 o;
  o[0] = (bf16_t)acc[0]; o[1] = (bf16_t)acc[1];
  o[2] = (bf16_t)acc[2]; o[3] = (bf16_t)acc[3];
  *(bf16x4*)(out + tid * 4) = o;
}

// ---------------------------------------------------------------------------
// Kernel 3: fused QKV+QPE GEMM (bf16 MFMA).  C[m][n] = sum_k Xb[m][k]*Wt[n][k]
//   M=32640, N=3200, K=1024.  Grid: x = N-tiles (fast) for X-tile L2 reuse.
// ---------------------------------------------------------------------------
__global__ __launch_bounds__(256) void qkv_gemm(const bf16_t* __restrict__ X,
                                                const bf16_t* __restrict__ Wt,
                                                bf16_t* __restrict__ QKV) {
  __shared__ bf16_t As[128 * 32];
  __shared__ bf16_t Bs[128 * 32];
  const int m0   = blockIdx.y * 128;
  const int n0   = blockIdx.x * 128;   // x fastest -> 25 blocks share X-tile
  const int tid  = threadIdx.x;
  const int wave = tid >> 6;
  const int lane = tid & 63;
  const int wm   = (wave >> 1) * 64;
  const int wn   = (wave & 1) * 64;
  const int qd   = lane >> 4;      // quad 0..3
  const int lr   = lane & 15;

  floatx4 acc[4][4] = {};

  // staging: 512 16B-chunks per tile; chunk c -> row c>>2, elem off (c&3)*8
  const int c0 = (wave * 2 + 0) * 64 + lane;
  const int c1 = (wave * 2 + 1) * 64 + lane;
  const int r0 = c0 >> 2, o0 = (c0 & 3) * 8;
  const int r1 = c1 >> 2, o1 = (c1 & 3) * 8;
  const bf16_t* xg0 = X + (size_t)(m0 + r0) * 1024 + o0;
  const bf16_t* xg1 = X + (size_t)(m0 + r1) * 1024 + o1;
  const bf16_t* wg0 = Wt + (size_t)(n0 + r0) * 1024 + o0;
  const bf16_t* wg1 = Wt + (size_t)(n0 + r1) * 1024 + o1;
  bf16_t* lA0 = As + (wave * 2 + 0) * 512;   // wave-uniform LDS base
  bf16_t* lA1 = As + (wave * 2 + 1) * 512;
  bf16_t* lB0 = Bs + (wave * 2 + 0) * 512;
  bf16_t* lB1 = Bs + (wave * 2 + 1) * 512;

  for (int kk = 0; kk < 1024; kk += 32) {
    GLDS16(xg0 + kk, lA0);
    GLDS16(xg1 + kk, lA1);
    GLDS16(wg0 + kk, lB0);
    GLDS16(wg1 + kk, lB1);
    __syncthreads();

    bf16x8 a[4], b[4];
#pragma unroll
    for (int im = 0; im < 4; ++im)
      a[im] = *(const bf16x8*)(As + (wm + im * 16 + lr) * 32 + qd * 8);
#pragma unroll
    for (int in = 0; in < 4; ++in)
      b[in] = *(const bf16x8*)(Bs + (wn + in * 16 + lr) * 32 + qd * 8);
#pragma unroll
    for (int im = 0; im < 4; ++im)
#pragma unroll
      for (int in = 0; in < 4; ++in)
        acc[im][in] = __builtin_amdgcn_mfma_f32_16x16x32_bf16(
            a[im], b[in], acc[im][in], 0, 0, 0);
    __syncthreads();
  }

  // epilogue: C/D layout col=lane&15, row=quad*4+reg  (verified m89)
#pragma unroll
  for (int im = 0; im < 4; ++im)
#pragma unroll
    for (int in = 0; in < 4; ++in)
#pragma unroll
      for (int r = 0; r < 4; ++r) {
        int m = m0 + wm + im * 16 + qd * 4 + r;
        int n = n0 + wn + in * 16 + lr;
        QKV[(size_t)m * kNC + n] = (bf16_t)acc[im][in][r];
      }
}

// ---------------------------------------------------------------------------
// Kernel 4: local attention.  One block per (u, head, batch).
// ---------------------------------------------------------------------------
__global__ __launch_bounds__(256) void attn_k(const bf16_t* __restrict__ QKV,
                                              float* __restrict__ OUT) {
  __shared__ float qs[12 * 132];
  __shared__ float ks[24 * 132];
  __shared__ float vs[24 * 132];
  __shared__ float qpes[156];
  __shared__ float p[12 * 16];

  const int u   = blockIdx.x;
  const int n   = blockIdx.y;
  const int b   = blockIdx.z;
  const int tid = threadIdx.x;
  const int t0  = u * 12 - 12;                 // time of context row c=0
  const size_t bbase = (size_t)b * kT;

  // ---- stage q (12 rows x 128, 16B loads / 16B LDS stores) ----
  if (tid < 192) {
    int row = tid >> 4, ch = tid & 15;
    bf16x8 v8 = *(const bf16x8*)(QKV + (bbase + u * 12 + row) * kNC + n * 128 + ch * 8);
    float4 lo = { (float)v8[0], (float)v8[1], (float)v8[2], (float)v8[3] };
    float4 hi = { (float)v8[4], (float)v8[5], (float)v8[6], (float)v8[7] };
    int o = row * 132 + ch * 8;
    *(float4*)(qs + o)     = lo;
    *(float4*)(qs + o + 4) = hi;
  }
  // ---- stage k, v (24 rows x 128) ----
  for (int i = tid; i < 24 * 16; i += 256) {
    int row = i >> 4, ch = i & 15;
    int t = t0 + row;
    int o = row * 132 + ch * 8;
    if (t < 0) {
      float4 z = {};
      *(float4*)(ks + o) = z; *(float4*)(ks + o + 4) = z;
      *(float4*)(vs + o) = z; *(float4*)(vs + o + 4) = z;
    } else {
      size_t base = (bbase + t) * kNC + n * 128 + ch * 8;
      bf16x8 k8 = *(const bf16x8*)(QKV + base + 1024);
      bf16x8 v8 = *(const bf16x8*)(QKV + base + 2048);
      float4 kl = { (float)k8[0], (float)k8[1], (float)k8[2], (float)k8[3] };
      float4 kh = { (float)k8[4], (float)k8[5], (float)k8[6], (float)k8[7] };
      float4 vl = { (float)v8[0], (float)v8[1], (float)v8[2], (float)v8[3] };
      float4 vh = { (float)v8[4], (float)v8[5], (float)v8[6], (float)v8[7] };
      *(float4*)(ks + o) = kl; *(float4*)(ks + o + 4) = kh;
      *(float4*)(vs + o) = vl; *(float4*)(vs + o + 4) = vh;
    }
  }
  // ---- stage precomputed q.pe term ----
  if (tid < 156) {
    int w = tid / 13, d = tid - w * 13;
    qpes[tid] = (float)QKV[(bbase + u * 12 + w) * kNC + 3072 + n * 13 + d];
  }
  __syncthreads();

  // ---- logits: 12 queries x 13 distances (float4 LDS reads) ----
  if (tid < 156) {
    int w = tid / 13, d = tid - w * 13;
    int t = u * 12 + w - d;
    float lg = -1e30f;
    if (t >= 0) {
      int cc = w - d + 12;                 // context row of that key
      const float* qp = qs + w * 132;
      const float* kp = ks + cc * 132;
      float acc = qpes[tid];
#pragma unroll
      for (int it = 0; it < 32; ++it) {
        float4 qv = *(const float4*)(qp + it * 4);
        float4 kv = *(const float4*)(kp + it * 4);
        acc += qv.x * kv.x + qv.y * kv.y + qv.z * kv.z + qv.w * kv.w;
      }
      // * H^-0.5 / CAP inside tanh, * CAP outside
      lg = 50.0f * tanhf(acc * 0.0017677669529663689f);
    }
    p[(tid / 13) * 16 + (tid % 13)] = lg;
  }
  __syncthreads();

  // ---- softmax per query row ----
  if (tid < 12) {
    float* pr = p + tid * 16;
    float mx = -1e30f;
#pragma unroll
    for (int d = 0; d < 13; ++d) mx = fmaxf(mx, pr[d]);
    float sum = 0.f;
    float e[13];
#pragma unroll
    for (int d = 0; d < 13; ++d) { e[d] = expf(pr[d] - mx); sum += e[d]; }
    float inv = 1.0f / sum;
#pragma unroll
    for (int d = 0; d < 13; ++d) pr[d] = e[d] * inv;
  }
  __syncthreads();

  // ---- PV: out[w][h4] = sum_d p[w][d] * v[w-d+12][h4]  (float4) ----
  for (int i = tid; i < 12 * 32; i += 256) {
    int w = i >> 5, c4 = i & 31;
    const float* pw = p + w * 16;
    float4 acc = {};
#pragma unroll
    for (int d = 0; d < 13; ++d) {
      float pd = pw[d];
      float4 v4 = *(const float4*)(vs + (w - d + 12) * 132 + c4 * 4);
      acc.x += pd * v4.x; acc.y += pd * v4.y;
      acc.z += pd * v4.z; acc.w += pd * v4.w;
    }
    *(float4*)(OUT + (bbase + u * 12 + w) * 1024 + n * 128 + c4 * 4) = acc;
  }
}

// ---------------------------------------------------------------------------
// Launch
// ---------------------------------------------------------------------------
extern "C" void kernel_launch(void* const* d_in, const int* in_sizes, int n_in,
                              void* d_out, int out_size, void* d_ws, size_t ws_size,
                              hipStream_t stream) {
  const float* x  = (const float*)d_in[0];
  // d_in[1] = mask (all True) and d_in[2] = causal_valid_mask are analytic; unused.
  const float* wq = (const float*)d_in[3];
  const float* wk = (const float*)d_in[4];
  const float* wv = (const float*)d_in[5];
  const float* pp = (const float*)d_in[6];

  char* ws = (char*)d_ws;
  float*  pe  = (float*)ws;                                   // 53 KB
  bf16_t* Wt  = (bf16_t*)(ws + (1u << 16));                   // 3200*1024*2 = 6.6 MB
  bf16_t* Xb  = (bf16_t*)(ws + (1u << 16) + 8u * 1024 * 1024);        // 66.8 MB
  bf16_t* QKV = (bf16_t*)(ws + (1u << 16) + 8u * 1024 * 1024 +
                          (size_t)kM * 1024 * 2);                      // 209 MB
  float* out = (float*)d_out;

  convert_x<<<kM * 1024 / (256 * 8), 256, 0, stream>>>(x, Xb);
  posemb_k<<<13, 256, 0, stream>>>(pp, pe);
  transpose_w<<<dim3(16, 16, 3), 256, 0, stream>>>(wq, wk, wv, Wt);
  pe2w<<<128, 256, 0, stream>>>(pe, Wt);
  qkv_gemm<<<dim3(kNC / 128, kM / 128), 256, 0, stream>>>(Xb, Wt, QKV);
  attn_k<<<dim3(kU, 8, 4), 256, 0, stream>>>(QKV, out);
}

// Round 4
// 614.671 us; speedup vs baseline: 1.2946x; 1.1888x over previous
//
#include <hip/hip_runtime.h>
#include <cstdint>
#include <cstddef>

// ---------------------------------------------------------------------------
// B=4, T=8160, D=1024, N=8 heads, H=128, W=12, L=12, R=0, C=24, CAP=50
// logit(qt,kt) = s*(q.(k + emb[qt-kt])), d = qt-kt in [0,12], softcap, softmax.
// Position term folded into the QKV GEMM:  q.pe_d = x . (Wq @ pe_d), appended
// as 128 extra B-rows (104 real (n,d) pairs + 24 zero pad) -> GEMM N = 3200.
// QKV row: [0,1024)=q [1024,2048)=k [2048,3072)=v [3072+n*13+d]=qpe.
// ---------------------------------------------------------------------------

typedef __bf16 bf16_t;
typedef float  floatx4 __attribute__((ext_vector_type(4)));
typedef __bf16 bf16x8  __attribute__((ext_vector_type(8)));
typedef __bf16 bf16x4  __attribute__((ext_vector_type(4)));

#define GLDS16(gp, lp)                                                        \
  __builtin_amdgcn_global_load_lds(                                           \
      (const __attribute__((address_space(1))) void*)(gp),                    \
      (__attribute__((address_space(3))) void*)(lp), 16, 0, 0)

static constexpr int kT     = 8160;
static constexpr int kM     = 4 * kT;    // 32640
static constexpr int kU     = kT / 12;   // 680
static constexpr int kNC    = 3200;      // GEMM N (3072 qkv + 128 qpe block)

// ---------------------------------------------------------------------------
// Kernel 0: convert x (fp32) -> bf16, 8 elements/thread.
// ---------------------------------------------------------------------------
__global__ __launch_bounds__(256) void convert_x(const float* __restrict__ X,
                                                 bf16_t* __restrict__ Xb) {
  const size_t i = ((size_t)blockIdx.x * 256 + threadIdx.x) * 8;
  float4 a = *(const float4*)(X + i);
  float4 b = *(const float4*)(X + i + 4);
  bf16x8 o;
  o[0] = (bf16_t)a.x; o[1] = (bf16_t)a.y; o[2] = (bf16_t)a.z; o[3] = (bf16_t)a.w;
  o[4] = (bf16_t)b.x; o[5] = (bf16_t)b.y; o[6] = (bf16_t)b.z; o[7] = (bf16_t)b.w;
  *(bf16x8*)(Xb + i) = o;
}

// ---------------------------------------------------------------------------
// Kernel 1: pe[d][f] = sum_dd ts(d)[dd] * pos_proj[dd][f]   (fp32)
// grid (13, 8), 512 threads: f-chunk of 128, dd split 4-way + LDS reduce.
// ---------------------------------------------------------------------------
__global__ __launch_bounds__(512) void posemb_k(const float* __restrict__ pp,
                                                float* __restrict__ pe) {
  __shared__ float st[1024];
  __shared__ float red[4][128];
  const int d   = blockIdx.x;          // 0..12
  const int fc  = blockIdx.y;          // 0..7
  const int tid = threadIdx.x;
  const float dpos = (float)d;
  for (int i = tid; i < 1024; i += 512) {
    int idx = i & 511;
    float freq = expf(-(float)idx * (9.2103403719761836f / 511.0f));
    float a = dpos * freq;
    st[i] = (i < 512) ? sinf(a) : cosf(a);
  }
  __syncthreads();
  const int part = tid >> 7;           // 0..3
  const int fl   = tid & 127;
  const int f    = fc * 128 + fl;
  float acc = 0.f;
  const int dd0 = part * 256;
  for (int dd = dd0; dd < dd0 + 256; ++dd)
    acc += st[dd] * pp[(size_t)dd * 1024 + f];
  red[part][fl] = acc;
  __syncthreads();
  if (tid < 128)
    pe[(size_t)d * 1024 + f] = red[0][fl] + red[1][fl] + red[2][fl] + red[3][fl];
}

// ---------------------------------------------------------------------------
// Kernel 2: transpose fp32 weights -> bf16 Wt[3072][1024] (row n = col n of W)
// ---------------------------------------------------------------------------
__global__ __launch_bounds__(256) void transpose_w(const float* __restrict__ Wq,
                                                   const float* __restrict__ Wk,
                                                   const float* __restrict__ Wv,
                                                   bf16_t* __restrict__ Wt) {
  __shared__ float tile[64][65];
  const int g = blockIdx.z;
  const float* W = (g == 0) ? Wq : (g == 1) ? Wk : Wv;
  bf16_t* O = Wt + (size_t)g * 1024 * 1024;
  const int k0 = blockIdx.x * 64, n0 = blockIdx.y * 64;
  const int col = threadIdx.x & 63, r4 = threadIdx.x >> 6;
#pragma unroll
  for (int i = 0; i < 16; ++i) {
    int row = i * 4 + r4;
    tile[row][col] = W[(size_t)(k0 + row) * 1024 + n0 + col];
  }
  __syncthreads();
#pragma unroll
  for (int i = 0; i < 16; ++i) {
    int row = i * 4 + r4;   // n offset
    O[(size_t)(n0 + row) * 1024 + k0 + col] = (bf16_t)tile[col][row];
  }
}

// ---------------------------------------------------------------------------
// Kernel 2b: W2 rows.  Wt[3072+idx][k] = sum_h pe[d][n*128+h]*Wt[n*128+h][k]
// ---------------------------------------------------------------------------
__global__ __launch_bounds__(256) void pe2w(const float* __restrict__ pe,
                                            bf16_t* __restrict__ Wt) {
  const int idx = blockIdx.x;              // 0..127
  const int tid = threadIdx.x;
  bf16_t* out = Wt + (size_t)(3072 + idx) * 1024;
  if (idx >= 104) {
    bf16x4 z = {};
    *(bf16x4*)(out + tid * 4) = z;
    return;
  }
  const int n = idx / 13, d = idx - n * 13;
  __shared__ float peh[128];
  if (tid < 128) peh[tid] = pe[(size_t)d * 1024 + n * 128 + tid];
  __syncthreads();
  float acc[4] = {};
  const bf16_t* wb = Wt + (size_t)(n * 128) * 1024 + tid * 4;
  for (int h = 0; h < 128; ++h) {
    bf16x4 w4 = *(const bf16x4*)(wb + (size_t)h * 1024);
    float s = peh[h];
    acc[0] += s * (float)w4[0];
    acc[1] += s * (float)w4[1];
    acc[2] += s * (float)w4[2];
    acc[3] += s * (float)w4[3];
  }
  bf16x4 o;
  o[0] = (bf16_t)acc[0]; o[1] = (bf16_t)acc[1];
  o[2] = (bf16_t)acc[2]; o[3] = (bf16_t)acc[3];
  *(bf16x4*)(out + tid * 4) = o;
}

// ---------------------------------------------------------------------------
// Kernel 3: fused QKV+QPE GEMM (bf16 MFMA).  C[m][n] = sum_k Xb[m][k]*Wt[n][k]
//   M=32640 (255 tiles), N=3200 (25 tiles).  Flat grid 6400 with XCD-ownership
//   remap: XCD j owns works [800j, 800j+800) = 32 consecutive m-tiles (800=32*25)
//   so each X-tile is fetched by exactly ONE XCD's L2.
// ---------------------------------------------------------------------------
__global__ __launch_bounds__(256) void qkv_gemm(const bf16_t* __restrict__ X,
                                                const bf16_t* __restrict__ Wt,
                                                bf16_t* __restrict__ QKV) {
  const int flat = blockIdx.x;
  const int xcd  = flat & 7;
  const int j    = flat >> 3;            // 0..799
  const int work = xcd * 800 + j;        // XCD-contiguous work id
  if (work >= 255 * 25) return;
  const int m0 = (work / 25) * 128;
  const int n0 = (work % 25) * 128;

  __shared__ bf16_t As[128 * 32];
  __shared__ bf16_t Bs[128 * 32];
  const int tid  = threadIdx.x;
  const int wave = tid >> 6;
  const int lane = tid & 63;
  const int wm   = (wave >> 1) * 64;
  const int wn   = (wave & 1) * 64;
  const int qd   = lane >> 4;      // quad 0..3
  const int lr   = lane & 15;

  floatx4 acc[4][4] = {};

  // staging: 512 16B-chunks per tile; chunk c -> row c>>2, elem off (c&3)*8
  const int c0 = (wave * 2 + 0) * 64 + lane;
  const int c1 = (wave * 2 + 1) * 64 + lane;
  const int r0 = c0 >> 2, o0 = (c0 & 3) * 8;
  const int r1 = c1 >> 2, o1 = (c1 & 3) * 8;
  const bf16_t* xg0 = X + (size_t)(m0 + r0) * 1024 + o0;
  const bf16_t* xg1 = X + (size_t)(m0 + r1) * 1024 + o1;
  const bf16_t* wg0 = Wt + (size_t)(n0 + r0) * 1024 + o0;
  const bf16_t* wg1 = Wt + (size_t)(n0 + r1) * 1024 + o1;
  bf16_t* lA0 = As + (wave * 2 + 0) * 512;   // wave-uniform LDS base
  bf16_t* lA1 = As + (wave * 2 + 1) * 512;
  bf16_t* lB0 = Bs + (wave * 2 + 0) * 512;
  bf16_t* lB1 = Bs + (wave * 2 + 1) * 512;

  for (int kk = 0; kk < 1024; kk += 32) {
    GLDS16(xg0 + kk, lA0);
    GLDS16(xg1 + kk, lA1);
    GLDS16(wg0 + kk, lB0);
    GLDS16(wg1 + kk, lB1);
    __syncthreads();

    bf16x8 a[4], b[4];
#pragma unroll
    for (int im = 0; im < 4; ++im)
      a[im] = *(const bf16x8*)(As + (wm + im * 16 + lr) * 32 + qd * 8);
#pragma unroll
    for (int in = 0; in < 4; ++in)
      b[in] = *(const bf16x8*)(Bs + (wn + in * 16 + lr) * 32 + qd * 8);
#pragma unroll
    for (int im = 0; im < 4; ++im)
#pragma unroll
      for (int in = 0; in < 4; ++in)
        acc[im][in] = __builtin_amdgcn_mfma_f32_16x16x32_bf16(
            a[im], b[in], acc[im][in], 0, 0, 0);
    __syncthreads();
  }

  // epilogue: C/D layout col=lane&15, row=quad*4+reg  (verified m89)
#pragma unroll
  for (int im = 0; im < 4; ++im)
#pragma unroll
    for (int in = 0; in < 4; ++in)
#pragma unroll
      for (int r = 0; r < 4; ++r) {
        int m = m0 + wm + im * 16 + qd * 4 + r;
        int n = n0 + wn + in * 16 + lr;
        QKV[(size_t)m * kNC + n] = (bf16_t)acc[im][in][r];
      }
}

// ---------------------------------------------------------------------------
// Kernel 4: local attention.  Flat grid 21760; XCD j owns u in [85j, 85j+85)
// for all (n,b) so overlapping kv rows of consecutive u stay in one L2.
// q,k staged as bf16 (ds_read_b128 = 8 elems); v as fp32 for PV.
// ---------------------------------------------------------------------------
__global__ __launch_bounds__(256) void attn_k(const bf16_t* __restrict__ QKV,
                                              float* __restrict__ OUT) {
  __shared__ bf16_t qs[12 * 136];      // stride 136 bf16 = 272 B (16B-aligned)
  __shared__ bf16_t ks[24 * 136];
  __shared__ float  vs[24 * 132];      // stride 132 f32 = 528 B (16B-aligned)
  __shared__ float  qpes[156];
  __shared__ float  p[12 * 16];

  const int flat = blockIdx.x;
  const int xcd  = flat & 7;
  const int jj   = flat >> 3;          // 0..2719
  const int u    = xcd * 85 + (jj % 85);
  const int rest = jj / 85;            // 0..31
  const int n    = rest & 7;
  const int b    = rest >> 3;
  const int tid  = threadIdx.x;
  const int t0   = u * 12 - 12;        // time of context row c=0
  const size_t bbase = (size_t)b * kT;

  // ---- stage q (12 rows x 128 bf16, raw 16B copies) ----
  if (tid < 192) {
    int row = tid >> 4, ch = tid & 15;
    bf16x8 q8 = *(const bf16x8*)(QKV + (bbase + u * 12 + row) * kNC + n * 128 + ch * 8);
    *(bf16x8*)(qs + row * 136 + ch * 8) = q8;
  }
  // ---- stage k (bf16) and v (fp32), 24 rows x 128 ----
  for (int i = tid; i < 24 * 16; i += 256) {
    int row = i >> 4, ch = i & 15;
    int t = t0 + row;
    int ko = row * 136 + ch * 8;
    int vo = row * 132 + ch * 8;
    if (t < 0) {
      bf16x8 z = {};
      *(bf16x8*)(ks + ko) = z;
      float4 z4 = {};
      *(float4*)(vs + vo) = z4; *(float4*)(vs + vo + 4) = z4;
    } else {
      size_t base = (bbase + t) * kNC + n * 128 + ch * 8;
      bf16x8 k8 = *(const bf16x8*)(QKV + base + 1024);
      bf16x8 v8 = *(const bf16x8*)(QKV + base + 2048);
      *(bf16x8*)(ks + ko) = k8;
      float4 vl = { (float)v8[0], (float)v8[1], (float)v8[2], (float)v8[3] };
      float4 vh = { (float)v8[4], (float)v8[5], (float)v8[6], (float)v8[7] };
      *(float4*)(vs + vo) = vl; *(float4*)(vs + vo + 4) = vh;
    }
  }
  // ---- stage precomputed q.pe term ----
  if (tid < 156) {
    int w = tid / 13, d = tid - w * 13;
    qpes[tid] = (float)QKV[(bbase + u * 12 + w) * kNC + 3072 + n * 13 + d];
  }
  __syncthreads();

  // ---- logits: 12 queries x 13 distances (bf16x8 LDS reads) ----
  if (tid < 156) {
    int w = tid / 13, d = tid - w * 13;
    int t = u * 12 + w - d;
    float lg = -1e30f;
    if (t >= 0) {
      int cc = w - d + 12;                 // context row of that key
      const bf16_t* qp = qs + w * 136;
      const bf16_t* kp = ks + cc * 136;
      float acc = qpes[tid];
#pragma unroll
      for (int it = 0; it < 16; ++it) {
        bf16x8 q8 = *(const bf16x8*)(qp + it * 8);
        bf16x8 k8 = *(const bf16x8*)(kp + it * 8);
#pragma unroll
        for (int jx = 0; jx < 8; ++jx) acc += (float)q8[jx] * (float)k8[jx];
      }
      // * H^-0.5 / CAP inside tanh, * CAP outside
      lg = 50.0f * tanhf(acc * 0.0017677669529663689f);
    }
    p[w * 16 + d] = lg;
  }
  __syncthreads();

  // ---- softmax per query row ----
  if (tid < 12) {
    float* pr = p + tid * 16;
    float mx = -1e30f;
#pragma unroll
    for (int d = 0; d < 13; ++d) mx = fmaxf(mx, pr[d]);
    float sum = 0.f;
    float e[13];
#pragma unroll
    for (int d = 0; d < 13; ++d) { e[d] = expf(pr[d] - mx); sum += e[d]; }
    float inv = 1.0f / sum;
#pragma unroll
    for (int d = 0; d < 13; ++d) pr[d] = e[d] * inv;
  }
  __syncthreads();

  // ---- PV: out[w][h4] = sum_d p[w][d] * v[w-d+12][h4]  (float4) ----
  for (int i = tid; i < 12 * 32; i += 256) {
    int w = i >> 5, c4 = i & 31;
    const float* pw = p + w * 16;
    float4 acc = {};
#pragma unroll
    for (int d = 0; d < 13; ++d) {
      float pd = pw[d];
      float4 v4 = *(const float4*)(vs + (w - d + 12) * 132 + c4 * 4);
      acc.x += pd * v4.x; acc.y += pd * v4.y;
      acc.z += pd * v4.z; acc.w += pd * v4.w;
    }
    *(float4*)(OUT + (bbase + u * 12 + w) * 1024 + n * 128 + c4 * 4) = acc;
  }
}

// ---------------------------------------------------------------------------
// Launch
// ---------------------------------------------------------------------------
extern "C" void kernel_launch(void* const* d_in, const int* in_sizes, int n_in,
                              void* d_out, int out_size, void* d_ws, size_t ws_size,
                              hipStream_t stream) {
  const float* x  = (const float*)d_in[0];
  // d_in[1] = mask (all True) and d_in[2] = causal_valid_mask are analytic; unused.
  const float* wq = (const float*)d_in[3];
  const float* wk = (const float*)d_in[4];
  const float* wv = (const float*)d_in[5];
  const float* pp = (const float*)d_in[6];

  char* ws = (char*)d_ws;
  float*  pe  = (float*)ws;                                   // 53 KB
  bf16_t* Wt  = (bf16_t*)(ws + (1u << 16));                   // 3200*1024*2 = 6.6 MB
  bf16_t* Xb  = (bf16_t*)(ws + (1u << 16) + 8u * 1024 * 1024);        // 66.8 MB
  bf16_t* QKV = (bf16_t*)(ws + (1u << 16) + 8u * 1024 * 1024 +
                          (size_t)kM * 1024 * 2);                      // 209 MB
  float* out = (float*)d_out;

  convert_x<<<kM * 1024 / (256 * 8), 256, 0, stream>>>(x, Xb);
  posemb_k<<<dim3(13, 8), 512, 0, stream>>>(pp, pe);
  transpose_w<<<dim3(16, 16, 3), 256, 0, stream>>>(wq, wk, wv, Wt);
  pe2w<<<128, 256, 0, stream>>>(pe, Wt);
  qkv_gemm<<<6400, 256, 0, stream>>>(Xb, Wt, QKV);
  attn_k<<<21760, 256, 0, stream>>>(QKV, out);
}